// Round 1
// baseline (1589.616 us; speedup 1.0000x reference)
//
#include <hip/hip_runtime.h>
#include <math.h>

#define T_LEN 1024
#define BATCH 512
#define DIN   12
#define HID   100
#define G4    400   // 4*HID

__device__ __forceinline__ float fast_exp2(float x) {
#if __has_builtin(__builtin_amdgcn_exp2f)
    return __builtin_amdgcn_exp2f(x);
#else
    return exp2f(x);
#endif
}

__device__ __forceinline__ float fast_rcp(float x) {
#if __has_builtin(__builtin_amdgcn_rcpf)
    return __builtin_amdgcn_rcpf(x);
#else
    return 1.0f / x;
#endif
}

// block = 512 threads (8 waves); grid = 256 blocks (2 batches each) -> 1 block/CU.
// __launch_bounds__(512, 2): 8 waves/block = 2 waves/EU -> VGPR cap 256 (plenty for wcol[100]).
__launch_bounds__(512, 2)
__global__ void lstm_fused_kernel(const float* __restrict__ x,
                                  const float* __restrict__ Wx,
                                  const float* __restrict__ Wh,
                                  const float* __restrict__ b,
                                  const float* __restrict__ Wd,
                                  const float* __restrict__ bd,
                                  float* __restrict__ out) {
    const int tid = threadIdx.x;
    const int b0  = blockIdx.x * 2;   // two batches per block

    // h double-buffered by timestep parity; gates; x row staging
    __shared__ __align__(16) float hbuf[2][2][HID];  // [parity][r][cell]
    __shared__ __align__(16) float za[2][G4];        // activated gates [r][col]
    __shared__ __align__(16) float xbuf[2][DIN];     // x[b_r, t, :]

    // Per-thread weight column in registers.
    // tid < 400          : Wh[:, tid]  (recurrent column)
    // 400 <= tid < 424   : Wd[:, d]    (projection column, r=(tid-400)/12, d=(tid-400)%12)
    float wcol[HID];
    float wx[DIN];
    float bias = 0.f;
    float bdv  = 0.f;
    int   proj_r = 0, proj_d = 0;

    if (tid < G4) {
#pragma unroll
        for (int k = 0; k < HID; ++k) wcol[k] = Wh[k * G4 + tid];
#pragma unroll
        for (int d = 0; d < DIN; ++d) wx[d] = Wx[d * G4 + tid];
        bias = b[tid];
    } else if (tid < G4 + 24) {
        const int idx = tid - G4;
        proj_r = idx / DIN;
        proj_d = idx - proj_r * DIN;
#pragma unroll
        for (int k = 0; k < HID; ++k) wcol[k] = Wd[k * DIN + proj_d];
        bdv = bd[proj_d];
    }

    // init h_{-1} = 0 and stage x_0
    if (tid < 2 * HID) hbuf[0][tid / HID][tid % HID] = 0.f;
    if (tid >= 224 && tid < 224 + 2 * DIN) {
        const int idx = tid - 224;
        const int r = idx / DIN, d = idx - r * DIN;
        xbuf[r][d] = x[((size_t)(b0 + r) * T_LEN + 0) * DIN + d];
    }
    float c = 0.f;   // cell state, valid for tid < 200
    __syncthreads();

    const float LOG2E = 1.4426950408889634f;

    // t in [0, T]: step T runs only the projection of h_{T-1}.
    for (int t = 0; t <= T_LEN; ++t) {
        const int cur = t & 1;   // hbuf[cur] holds h_{t-1}

        // ---------------- Phase A: gate matmul + projection of previous h -------------
        if (tid < G4 + 24) {
            const bool mm = (tid < G4);
            if ((mm && t < T_LEN) || (!mm && t > 0)) {
                float z0 = 0.f, z1 = 0.f;
                const float* h0 = hbuf[cur][0];
                const float* h1 = hbuf[cur][1];
#pragma unroll
                for (int k = 0; k < HID; k += 4) {
                    const float4 a4 = *(const float4*)(h0 + k);
                    const float4 b4 = *(const float4*)(h1 + k);
                    z0 += a4.x * wcol[k]     + a4.y * wcol[k + 1]
                        + a4.z * wcol[k + 2] + a4.w * wcol[k + 3];
                    z1 += b4.x * wcol[k]     + b4.y * wcol[k + 1]
                        + b4.z * wcol[k + 2] + b4.w * wcol[k + 3];
                }
                if (mm) {
                    // add input projection x_t @ Wx[:, tid] + b[tid]
                    float xg0 = bias, xg1 = bias;
#pragma unroll
                    for (int d = 0; d < DIN; ++d) {
                        xg0 += xbuf[0][d] * wx[d];
                        xg1 += xbuf[1][d] * wx[d];
                    }
                    z0 += xg0;
                    z1 += xg1;
                    // gates: [0,100)=i sig, [100,200)=f sig, [200,300)=g tanh, [300,400)=o sig
                    const bool is_g = (tid >= 2 * HID) && (tid < 3 * HID);
                    float s0, s1;
                    {
                        const float xs = is_g ? 2.f * z0 : z0;
                        const float e  = fast_exp2(-LOG2E * xs);
                        const float s  = fast_rcp(1.f + e);
                        s0 = is_g ? 2.f * s - 1.f : s;
                    }
                    {
                        const float xs = is_g ? 2.f * z1 : z1;
                        const float e  = fast_exp2(-LOG2E * xs);
                        const float s  = fast_rcp(1.f + e);
                        s1 = is_g ? 2.f * s - 1.f : s;
                    }
                    za[0][tid] = s0;
                    za[1][tid] = s1;
                } else {
                    // projection of h_{t-1} -> out[b, t-1, :]
                    const float zr = (proj_r == 0) ? z0 : z1;
                    out[((size_t)(b0 + proj_r) * T_LEN + (t - 1)) * DIN + proj_d] = zr + bdv;
                }
            }
        }
        __syncthreads();

        // ---------------- Phase B: cell update + next-x staging ----------------------
        if (t < T_LEN) {
            if (tid < 2 * HID) {
                const int r = tid / HID, j = tid - r * HID;
                const float gi = za[r][j];
                const float gf = za[r][HID + j];
                const float gg = za[r][2 * HID + j];
                const float go = za[r][3 * HID + j];
                c = gf * c + gi * gg;
                // tanh(c) = 2*sigmoid(2c) - 1
                const float e  = fast_exp2(-2.f * LOG2E * c);
                const float th = 2.f * fast_rcp(1.f + e) - 1.f;
                hbuf[cur ^ 1][r][j] = go * th;
            }
            if (tid >= 224 && tid < 224 + 2 * DIN && (t + 1) < T_LEN) {
                const int idx = tid - 224;
                const int r = idx / DIN, d = idx - r * DIN;
                xbuf[r][d] = x[((size_t)(b0 + r) * T_LEN + (t + 1)) * DIN + d];
            }
        }
        __syncthreads();
    }
}

extern "C" void kernel_launch(void* const* d_in, const int* in_sizes, int n_in,
                              void* d_out, int out_size, void* d_ws, size_t ws_size,
                              hipStream_t stream) {
    const float* x  = (const float*)d_in[0];
    const float* Wx = (const float*)d_in[1];
    const float* Wh = (const float*)d_in[2];
    const float* b  = (const float*)d_in[3];
    const float* Wd = (const float*)d_in[4];
    const float* bd = (const float*)d_in[5];
    float* out = (float*)d_out;

    lstm_fused_kernel<<<BATCH / 2, 512, 0, stream>>>(x, Wx, Wh, b, Wd, bd, out);
}